// Round 7
// baseline (343.107 us; speedup 1.0000x reference)
//
#include <hip/hip_runtime.h>
#include <hip/hip_bf16.h>
#include <hip/hip_fp16.h>
#include <math.h>

// Problem constants (fixed-shape problem)
#define N_NODES 50000
#define FIN     32
#define HID     64
#define HC      128     // HEADS*HID
#define NE      800000
#define NET     850000  // NE + N self loops
#define NI      10000   // interface nodes
#define NG      50      // graphs
#define PB      8       // pooling blocks per graph

typedef _Float16 half8 __attribute__((ext_vector_type(8)));
typedef float float4v __attribute__((ext_vector_type(4)));

__device__ __forceinline__ float lrelu(float x) { return fmaxf(x, 0.2f * x); }

// order-preserving float->uint encoding for atomicMax; 0 == "less than any float"
__device__ __forceinline__ unsigned fenc(float f) {
  unsigned u = __float_as_uint(f);
  return (u & 0x80000000u) ? ~u : (u | 0x80000000u);
}
__device__ __forceinline__ float fdec(unsigned u) {
  return (u & 0x80000000u) ? __uint_as_float(u ^ 0x80000000u) : __uint_as_float(~u);
}

__device__ __forceinline__ int rli(int v, int l) {
  return __builtin_amdgcn_readlane(v, l);
}

// ---------------- CSR build (unordered buckets, rank from histogram) ----------------
__global__ void k_histrank(const int* __restrict__ ei, int* __restrict__ deg,
                           int* __restrict__ rank) {
  int e = blockIdx.x * blockDim.x + threadIdx.x;
  if (e >= NET) return;
  int d = (e < NE) ? ei[NE + e] : (e - NE);
  rank[e] = atomicAdd(&deg[d], 1);
}

__global__ void k_base(const int* __restrict__ deg, int* __restrict__ start,
                       int* __restrict__ gcur) {
  __shared__ int buf[256];
  __shared__ int basesh;
  int t = threadIdx.x;
  int i = blockIdx.x * 256 + t;
  int v = (i < N_NODES) ? deg[i] : 0;
  buf[t] = v; __syncthreads();
  for (int off = 1; off < 256; off <<= 1) {
    int a = (t >= off) ? buf[t - off] : 0;
    __syncthreads();
    buf[t] += a;
    __syncthreads();
  }
  if (t == 255) basesh = atomicAdd(gcur, buf[255]);
  __syncthreads();
  if (i < N_NODES) start[i] = basesh + buf[t] - v;
}

// edge record: 8B {src*256 (byte offset into xl2h), half2(1/ea.x, 1/ea.y)}
__global__ void k_scatter(const int* __restrict__ ei, const float* __restrict__ eattr,
                          const int* __restrict__ start, const int* __restrict__ rank,
                          int2* __restrict__ erec) {
  int e = blockIdx.x * blockDim.x + threadIdx.x;
  if (e >= NET) return;
  int s, d; float ex, ey;
  if (e < NE) {
    s = ei[e]; d = ei[NE + e];
    float2 ea = ((const float2*)eattr)[e];
    ex = 1.0f / ea.x; ey = 1.0f / ea.y;
  } else {
    s = d = e - NE; ex = 0.f; ey = 0.f;
  }
  int pos = start[d] + rank[e];
  __half2 ea2 = __floats2half2_rn(ex, ey);
  erec[pos] = make_int2(s << 8, *(int*)&ea2);
}

// ---------------- per-layer node linear via MFMA ----------------
// xl = h @ W  ([N x F] x [F x 128]) with fp16 inputs / fp32 accumulate.
// Block = 256 thr (4 waves), M-tile = 16 nodes (3125 blocks exactly).
template <int F>
__global__ __launch_bounds__(256) void k_linear_mfma(
    const float* __restrict__ h, const float* __restrict__ W,
    const float* __restrict__ attl, const float* __restrict__ attr,
    __half2* __restrict__ xl2h, float* __restrict__ al, float* __restrict__ ar) {
  __shared__ _Float16 hA[16 * F];
  __shared__ _Float16 hC[16 * 128];
  __shared__ float redl[16 * 4], redr[16 * 4];
  const int w = threadIdx.x >> 6, lane = threadIdx.x & 63;
  const int m = lane & 15, q = lane >> 4;
  const int n0 = blockIdx.x * 16;

  // stage A tile (16 consecutive node rows) as fp16
  for (int i = threadIdx.x; i < 16 * F; i += 256)
    hA[i] = (_Float16)h[(size_t)n0 * F + i];
  __syncthreads();

  half8 a0, a1;
#pragma unroll
  for (int j = 0; j < 8; j++) a0[j] = hA[m * F + q * 8 + j];
  if constexpr (F == 64) {
#pragma unroll
    for (int j = 0; j < 8; j++) a1[j] = hA[m * F + 32 + q * 8 + j];
  }

  const int c0 = w * 32;
  float4v acc[2];
  float pl[4] = {0.f, 0.f, 0.f, 0.f}, pr[4] = {0.f, 0.f, 0.f, 0.f};
#pragma unroll
  for (int t = 0; t < 2; t++) {
    const int colg = c0 + t * 16 + m;
    half8 b0;
#pragma unroll
    for (int j = 0; j < 8; j++) b0[j] = (_Float16)W[(q * 8 + j) * HC + colg];
    float4v z = {0.f, 0.f, 0.f, 0.f};
    acc[t] = __builtin_amdgcn_mfma_f32_16x16x32_f16(a0, b0, z, 0, 0, 0);
    if constexpr (F == 64) {
      half8 b1;
#pragma unroll
      for (int j = 0; j < 8; j++) b1[j] = (_Float16)W[(32 + q * 8 + j) * HC + colg];
      acc[t] = __builtin_amdgcn_mfma_f32_16x16x32_f16(a1, b1, acc[t], 0, 0, 0);
    }
    const float atl = attl[colg], atr = attr[colg];
#pragma unroll
    for (int reg = 0; reg < 4; reg++) {
      float val = acc[t][reg];
      hC[(q * 4 + reg) * 128 + colg] = (_Float16)val;
      pl[reg] += val * atl;
      pr[reg] += val * atr;
    }
  }
  // reduce attention dots over the 16 cols held within each quad
#pragma unroll
  for (int off = 1; off < 16; off <<= 1) {
#pragma unroll
    for (int reg = 0; reg < 4; reg++) {
      pl[reg] += __shfl_xor(pl[reg], off, 64);
      pr[reg] += __shfl_xor(pr[reg], off, 64);
    }
  }
  if (m == 0) {
#pragma unroll
    for (int reg = 0; reg < 4; reg++) {
      redl[(q * 4 + reg) * 4 + w] = pl[reg];
      redr[(q * 4 + reg) * 4 + w] = pr[reg];
    }
  }
  __syncthreads();
  if (threadIdx.x < 32) {
    int node = threadIdx.x >> 1, head = threadIdx.x & 1;
    al[(n0 + node) * 2 + head] = redl[node * 4 + head * 2] + redl[node * 4 + head * 2 + 1];
    ar[(n0 + node) * 2 + head] = redr[node * 4 + head * 2] + redr[node * 4 + head * 2 + 1];
  }
  for (int i = threadIdx.x; i < 16 * 64; i += 256) {
    int node = i >> 6, cc = i & 63;
    xl2h[(size_t)(n0 + node) * HID + cc] =
        __halves2half2(hC[node * 128 + cc], hC[node * 128 + 64 + cc]);
  }
}

// ---------------- per-layer edge aggregation ----------------
// 1 wave per dst node. Strip-parallel scores (p packed to half2 per edge:
// one readlane broadcast), serial gather loop unrolled x8 with v_pk_fma_f16
// into 4 rotating half2 accumulators (~5 VALU/edge). 32-bit saddr addressing.
__global__ void k_aggregate(const __half2* __restrict__ xl2h, const float* __restrict__ alp,
                            const float2* __restrict__ ar2, const int* __restrict__ start,
                            const int* __restrict__ degarr, const int2* __restrict__ erec,
                            const float* __restrict__ eW2, const float* __restrict__ eb1,
                            const float* __restrict__ bconv1, float* __restrict__ hout) {
  const int gid = blockIdx.x * 4 + (threadIdx.x >> 6);
  if (gid >= N_NODES) return;
  const int lane = threadIdx.x & 63;
  const int lane4 = lane << 2;
  const int o0 = start[gid];
  const int deg = degarr[gid];
  const float2 arv = ar2[gid];
  const char* xbase = (const char*)xl2h;
  const char* albase = (const char*)alp;

  const __half2 hz = __floats2half2_rn(0.f, 0.f);
  __half2 accA = hz, accB = hz, accC = hz, accD = hz;
  float ld0 = 0.f, ld1 = 0.f, lex0 = 0.f, ley0 = 0.f, lex1 = 0.f, ley1 = 0.f;
  for (int base = 0; base < deg; base += 64) {
    int j = base + lane;
    int soff = 0, pbits = 0;
    if (j < deg) {
      int2 r = erec[o0 + j];
      soff = r.x;
      float2 eaf = __half22float2(*(__half2*)&r.y);
      float2 alv = *(const float2*)(albase + (soff >> 5));
      float p0 = __expf(lrelu(alv.x + arv.x));
      float p1 = __expf(lrelu(alv.y + arv.y));
      ld0 += p0; ld1 += p1;
      lex0 += p0 * eaf.x; ley0 += p0 * eaf.y;
      lex1 += p1 * eaf.x; ley1 += p1 * eaf.y;
      __half2 ph = __floats2half2_rn(p0, p1);
      pbits = *(int*)&ph;
    }
    int slen = min(64, deg - base);
    int j2 = 0;
    for (; j2 + 8 <= slen; j2 += 8) {
      int so0 = rli(soff, j2),     so1 = rli(soff, j2 + 1);
      int so2 = rli(soff, j2 + 2), so3 = rli(soff, j2 + 3);
      int so4 = rli(soff, j2 + 4), so5 = rli(soff, j2 + 5);
      int so6 = rli(soff, j2 + 6), so7 = rli(soff, j2 + 7);
      __half2 x0 = *(const __half2*)(xbase + so0 + lane4);
      __half2 x1 = *(const __half2*)(xbase + so1 + lane4);
      __half2 x2 = *(const __half2*)(xbase + so2 + lane4);
      __half2 x3 = *(const __half2*)(xbase + so3 + lane4);
      __half2 x4 = *(const __half2*)(xbase + so4 + lane4);
      __half2 x5 = *(const __half2*)(xbase + so5 + lane4);
      __half2 x6 = *(const __half2*)(xbase + so6 + lane4);
      __half2 x7 = *(const __half2*)(xbase + so7 + lane4);
      int pw0 = rli(pbits, j2),     pw1 = rli(pbits, j2 + 1);
      int pw2 = rli(pbits, j2 + 2), pw3 = rli(pbits, j2 + 3);
      int pw4 = rli(pbits, j2 + 4), pw5 = rli(pbits, j2 + 5);
      int pw6 = rli(pbits, j2 + 6), pw7 = rli(pbits, j2 + 7);
      accA = __hfma2(*(__half2*)&pw0, x0, accA);
      accB = __hfma2(*(__half2*)&pw1, x1, accB);
      accC = __hfma2(*(__half2*)&pw2, x2, accC);
      accD = __hfma2(*(__half2*)&pw3, x3, accD);
      accA = __hfma2(*(__half2*)&pw4, x4, accA);
      accB = __hfma2(*(__half2*)&pw5, x5, accB);
      accC = __hfma2(*(__half2*)&pw6, x6, accC);
      accD = __hfma2(*(__half2*)&pw7, x7, accD);
    }
    for (; j2 + 4 <= slen; j2 += 4) {
      int so0 = rli(soff, j2),     so1 = rli(soff, j2 + 1);
      int so2 = rli(soff, j2 + 2), so3 = rli(soff, j2 + 3);
      __half2 x0 = *(const __half2*)(xbase + so0 + lane4);
      __half2 x1 = *(const __half2*)(xbase + so1 + lane4);
      __half2 x2 = *(const __half2*)(xbase + so2 + lane4);
      __half2 x3 = *(const __half2*)(xbase + so3 + lane4);
      int pw0 = rli(pbits, j2),     pw1 = rli(pbits, j2 + 1);
      int pw2 = rli(pbits, j2 + 2), pw3 = rli(pbits, j2 + 3);
      accA = __hfma2(*(__half2*)&pw0, x0, accA);
      accB = __hfma2(*(__half2*)&pw1, x1, accB);
      accC = __hfma2(*(__half2*)&pw2, x2, accC);
      accD = __hfma2(*(__half2*)&pw3, x3, accD);
    }
    for (; j2 < slen; j2++) {
      int so0 = rli(soff, j2);
      __half2 x0 = *(const __half2*)(xbase + so0 + lane4);
      int pw0 = rli(pbits, j2);
      accA = __hfma2(*(__half2*)&pw0, x0, accA);
    }
  }
  float2 fA = __half22float2(accA), fB = __half22float2(accB);
  float2 fC = __half22float2(accC), fD = __half22float2(accD);
  float acc0 = (fA.x + fB.x) + (fC.x + fD.x);
  float acc1 = (fA.y + fB.y) + (fC.y + fD.y);
#pragma unroll
  for (int off = 32; off; off >>= 1) {
    ld0  += __shfl_xor(ld0, off, 64);
    ld1  += __shfl_xor(ld1, off, 64);
    lex0 += __shfl_xor(lex0, off, 64);
    ley0 += __shfl_xor(ley0, off, 64);
    lex1 += __shfl_xor(lex1, off, 64);
    ley1 += __shfl_xor(ley1, off, 64);
  }
  float t0 = acc0 + eW2[lane]      * lex0 + eW2[HC + lane]      * ley0 + eb1[lane]      * ld0;
  float t1 = acc1 + eW2[64 + lane] * lex1 + eW2[HC + 64 + lane] * ley1 + eb1[64 + lane] * ld1;
  float r = 0.5f * (t0 / (ld0 + 1e-16f) + t1 / (ld1 + 1e-16f)) + bconv1[lane];
  hout[(size_t)gid * HID + lane] = tanhf(r);
}

// ---------------- pooling ----------------
__global__ void k_ranges(const int* __restrict__ ipos, const int* __restrict__ batch,
                         int* __restrict__ gstart) {
  int i = blockIdx.x * blockDim.x + threadIdx.x;
  if (i >= NI) return;
  int bi = batch[ipos[i]];
  int prev = (i > 0) ? batch[ipos[i - 1]] : -1;
  for (int g = prev + 1; g <= bi; g++) gstart[g] = i;
  if (i == NI - 1)
    for (int g = bi + 1; g <= NG; g++) gstart[g] = NI;
}

__global__ void k_pool(const float* __restrict__ h0, const float* __restrict__ h1,
                       const float* __restrict__ h2, const int* __restrict__ ipos,
                       const int* __restrict__ gstart, const float* __restrict__ gate_w,
                       const float* __restrict__ gate_b, float* __restrict__ add,
                       unsigned* __restrict__ mxE, float* __restrict__ cnt,
                       float* __restrict__ attp, float* __restrict__ aden) {
  __shared__ float red[4][3 * HID + 2];
  const int g = blockIdx.x / PB, m = blockIdx.x % PB;
  const int w = threadIdx.x >> 6, lane = threadIdx.x & 63;
  const int s0 = gstart[g], s1 = gstart[g + 1];
  const int len = s1 - s0;
  const int b0 = s0 + (len * m) / PB;
  const int b1 = s0 + (len * (m + 1)) / PB;
  const float gwv = gate_w[lane];
  const float gbv = gate_b[0];

  float padd = 0.f, pmax = -1e30f, pattp = 0.f, paden = 0.f, pcnt = 0.f;
  for (int i = b0 + w; i < b1; i += 4) {
    size_t node = (size_t)ipos[i] * HID + lane;
    float v = fmaxf(fmaxf(h0[node], h1[node]), h2[node]);
    padd += v;
    pmax = fmaxf(pmax, v);
    float gv = v * gwv;
#pragma unroll
    for (int off = 32; off; off >>= 1) gv += __shfl_xor(gv, off, 64);
    float e = __expf(gv + gbv);   // |gate| << 88: exp-safe without max shift
    pattp += e * v;
    paden += e;   // wave-uniform
    pcnt += 1.f;
  }
  red[w][lane] = padd;
  red[w][HID + lane] = pmax;
  red[w][2 * HID + lane] = pattp;
  if (lane == 0) { red[w][3 * HID] = paden; red[w][3 * HID + 1] = pcnt; }
  __syncthreads();
  if (w == 0) {
    float addv  = red[0][lane] + red[1][lane] + red[2][lane] + red[3][lane];
    float maxv  = fmaxf(fmaxf(red[0][HID + lane], red[1][HID + lane]),
                        fmaxf(red[2][HID + lane], red[3][HID + lane]));
    float attpv = red[0][2 * HID + lane] + red[1][2 * HID + lane] +
                  red[2][2 * HID + lane] + red[3][2 * HID + lane];
    atomicAdd(&add[g * HID + lane], addv);
    atomicMax(&mxE[g * HID + lane], fenc(maxv));
    atomicAdd(&attp[g * HID + lane], attpv);
    if (lane == 0) {
      atomicAdd(&aden[g], red[0][3 * HID] + red[1][3 * HID] + red[2][3 * HID] + red[3][3 * HID]);
      atomicAdd(&cnt[g],  red[0][3 * HID + 1] + red[1][3 * HID + 1] +
                          red[2][3 * HID + 1] + red[3][3 * HID + 1]);
    }
  }
}

__global__ void k_final(const float* __restrict__ add, const float* __restrict__ cnt,
                        const float* __restrict__ attp, const float* __restrict__ aden,
                        const unsigned* __restrict__ mxE, const float* __restrict__ lin1_w,
                        const float* __restrict__ lin1_b, const float* __restrict__ lin2_w,
                        const float* __restrict__ lin2_b, float* __restrict__ out) {
  __shared__ float pooled[4 * HID];
  __shared__ float zred[2 * HID];
  int g = blockIdx.x, t = threadIdx.x;  // 256 threads
  if (t < HID)            pooled[t] = add[g * HID + t];
  else if (t < 2 * HID)   pooled[t] = add[g * HID + (t - HID)] / fmaxf(cnt[g], 1.f);
  else if (t < 3 * HID)   pooled[t] = attp[g * HID + (t - 2 * HID)] / (aden[g] + 1e-16f);
  else                    pooled[t] = fdec(mxE[g * HID + (t - 3 * HID)]);
  __syncthreads();
  if (t < 2 * HID) {
    float z = lin1_b[t];
    for (int k = 0; k < 4 * HID; k++) z += pooled[k] * lin1_w[k * (2 * HID) + t];
    z = tanhf(z);
    zred[t] = z * lin2_w[t];
  }
  __syncthreads();
  if (t == 0) {
    float s = 0.f;
    for (int k = 0; k < 2 * HID; k++) s += zred[k];
    out[g] = s + lin2_b[0];
  }
}

extern "C" void kernel_launch(void* const* d_in, const int* in_sizes, int n_in,
                              void* d_out, int out_size, void* d_ws, size_t ws_size,
                              hipStream_t stream) {
  const float* x      = (const float*)d_in[0];
  const int*   ei     = (const int*)d_in[1];
  const float* eattr  = (const float*)d_in[2];
  const int*   batch  = (const int*)d_in[3];
  const int*   ipos   = (const int*)d_in[4];
  // d_in[5] = graph_num scalar (G=50, hardcoded)
  const float* W0     = (const float*)d_in[6];
  const float* attl0  = (const float*)d_in[7];
  const float* attr0  = (const float*)d_in[8];
  const float* W12    = (const float*)d_in[9];
  const float* attl12 = (const float*)d_in[10];
  const float* attr12 = (const float*)d_in[11];
  const float* eW     = (const float*)d_in[12];
  const float* eb     = (const float*)d_in[13];
  const float* bconv  = (const float*)d_in[14];
  const float* gate_w = (const float*)d_in[15];
  const float* gate_b = (const float*)d_in[16];
  const float* lin1_w = (const float*)d_in[17];
  const float* lin1_b = (const float*)d_in[18];
  const float* lin2_w = (const float*)d_in[19];
  const float* lin2_b = (const float*)d_in[20];
  float* out = (float*)d_out;

  char* ws = (char*)d_ws;
  size_t off = 0;
  auto alloc = [&](size_t elems) {
    void* p = ws + off;
    off += ((elems * 4 + 15) / 16) * 16;   // 16B-aligned slots
    return p;
  };
  // ---- zero-init region (contiguous, one memset) ----
  int*      deg    = (int*)alloc(N_NODES);
  int*      gcur   = (int*)alloc(4);
  float*    addp   = (float*)alloc(NG * HID);
  float*    attp   = (float*)alloc(NG * HID);
  unsigned* mxE    = (unsigned*)alloc(NG * HID);
  float*    cnt    = (float*)alloc(64);
  float*    aden   = (float*)alloc(64);
  size_t zbytes = off;
  // ---- rest ----
  int*     gstart = (int*)alloc(NG + 4);
  int*     start  = (int*)alloc(N_NODES);
  int*     rank   = (int*)alloc(NET);
  int2*    erec   = (int2*)alloc((size_t)NET * 2);           // 8B records
  __half2* xl2h   = (__half2*)alloc((size_t)N_NODES * HID);  // 4B each
  float*   al     = (float*)alloc((size_t)N_NODES * 2);
  float*   arr    = (float*)alloc((size_t)N_NODES * 2);
  float*   h0     = (float*)alloc((size_t)N_NODES * HID);
  float*   h1     = (float*)alloc((size_t)N_NODES * HID);
  float*   h2     = (float*)alloc((size_t)N_NODES * HID);
  (void)ws_size; (void)in_sizes; (void)n_in; (void)out_size;

  hipMemsetAsync(d_ws, 0, zbytes, stream);
  k_histrank<<<(NET + 255) / 256, 256, 0, stream>>>(ei, deg, rank);
  k_base<<<(N_NODES + 255) / 256, 256, 0, stream>>>(deg, start, gcur);
  k_scatter<<<(NET + 255) / 256, 256, 0, stream>>>(ei, eattr, start, rank, erec);
  k_ranges<<<(NI + 255) / 256, 256, 0, stream>>>(ipos, batch, gstart);

  // layer 0
  k_linear_mfma<FIN><<<N_NODES / 16, 256, 0, stream>>>(x, W0, attl0, attr0, xl2h, al, arr);
  k_aggregate<<<N_NODES / 4, 256, 0, stream>>>(xl2h, al, (const float2*)arr,
                                               start, deg, erec, eW, eb, bconv, h0);
  // layer 1
  k_linear_mfma<HID><<<N_NODES / 16, 256, 0, stream>>>(h0, W12, attl12, attr12, xl2h, al, arr);
  k_aggregate<<<N_NODES / 4, 256, 0, stream>>>(xl2h, al, (const float2*)arr,
                                               start, deg, erec, eW + 2 * HC, eb + HC,
                                               bconv + HID, h1);
  // layer 2
  k_linear_mfma<HID><<<N_NODES / 16, 256, 0, stream>>>(h1, W12 + (size_t)HID * HC,
                                                       attl12 + HC, attr12 + HC, xl2h, al, arr);
  k_aggregate<<<N_NODES / 4, 256, 0, stream>>>(xl2h, al, (const float2*)arr,
                                               start, deg, erec, eW + 4 * HC, eb + 2 * HC,
                                               bconv + 2 * HID, h2);

  k_pool<<<NG * PB, 256, 0, stream>>>(h0, h1, h2, ipos, gstart, gate_w, gate_b,
                                      addp, mxE, cnt, attp, aden);
  k_final<<<NG, 256, 0, stream>>>(addp, cnt, attp, aden, mxE, lin1_w, lin1_b, lin2_w, lin2_b, out);
}